// Round 7
// baseline (146.349 us; speedup 1.0000x reference)
//
#include <hip/hip_runtime.h>
#include <hip/hip_bf16.h>

// CharLSTM: B=128, TW=256, TC=25, V=128, D=32, H=64 (4H=256), N=32768 seqs.
//
// R7 = R6 + two-group intra-wave pipeline:
//  Block = 32 sequences as TWO independent groups of 16 (A: rows 0-15,
//  B: rows 16-31). Same U fragments serve both. Per timestep:
//    MFMA A ; MFMA B ; prefetch EWr ; act A ; act B ; barrier
//  B's MFMAs overlap A's transcendental chain (independent), and A/B act
//  chains interleave (8 r-chains) -> fills the ~39% VALU-idle that R6
//  exposed (R6 cut instructions, VALUBusy fell 65->61, time flat =>
//  latency-bound, not issue-bound).
//  VGPR ~200 -> 2 waves/SIMD; hiding is now intra-wave so that's OK.

#define SEQ_M 32
#define TC_LEN 25
#define H_N 64
#define D_N 32
#define G4_N 256
#define V_N 128

typedef __attribute__((ext_vector_type(8))) short bf16x8;
typedef __attribute__((ext_vector_type(4))) float f32x4;
typedef __attribute__((ext_vector_type(4))) int i32x4;

#define SCALE_SIG (-1.4426950408889634f)   /* -log2(e)  */
#define SCALE_G   ( 2.8853900817779268f)   /* 2*log2(e) */

__device__ __forceinline__ ushort bf16_rne(float x) {
    const uint u = __float_as_uint(x);
    return (ushort)((u + 0x7fffu + ((u >> 16) & 1u)) >> 16);
}
__device__ __forceinline__ float bf16_tof(ushort h) {
    return __uint_as_float(((uint)h) << 16);
}
// swizzled byte offset into a [16][64] bf16 (2 KB) tile
__device__ __forceinline__ int hswz(int row, int kbyte) {
    const int b = row * 128 + kbyte;
    return b ^ ((row & 7) << 4);
}

// ---- prologue: EWr[v][c16][tile] = ((E.W)[v][tile*64+c16] + b) * gate_scale ----
__global__ void ew_precompute(const float* __restrict__ E,
                              const float* __restrict__ W,
                              const float* __restrict__ b,
                              float* __restrict__ EWr) {
    const int v = blockIdx.x;
    const int j = threadIdx.x;           // output col = (j>>6)*64 + (j&63)
    float acc = b[j];
#pragma unroll
    for (int d = 0; d < D_N; ++d)
        acc = fmaf(E[v * D_N + d], W[d * G4_N + j], acc);
    const int tile = j >> 6, c16 = j & 63;
    const float scale = (tile == 2) ? SCALE_G : SCALE_SIG;
    EWr[v * G4_N + c16 * 4 + tile] = acc * scale;
}

// activation + cell update + swizzled h-write for one 16-row group
__device__ __forceinline__ void act_group(f32x4 acc[4], float c[4],
                                          char* hn_hi, char* hn_lo,
                                          const int* offW) {
    float m1[4], Pf[4], num[4];
#pragma unroll
    for (int r = 0; r < 4; ++r) {
        const float A = __builtin_amdgcn_exp2f(acc[0][r]);   // e^-zi
        const float B = __builtin_amdgcn_exp2f(acc[1][r]);   // e^-zf
        const float C = __builtin_amdgcn_exp2f(acc[2][r]);   // e^2zg
        const float di = 1.0f + A, df = 1.0f + B, dg = 1.0f + C;
        m1[r]  = di * dg;
        Pf[r]  = m1[r] * df;
        num[r] = fmaf(c[r], m1[r], (C - 1.0f) * df);
    }
    const float Q01 = __builtin_amdgcn_rcpf(Pf[0] * Pf[1]);
    const float Q23 = __builtin_amdgcn_rcpf(Pf[2] * Pf[3]);
    c[0] = num[0] * (Q01 * Pf[1]);
    c[1] = num[1] * (Q01 * Pf[0]);
    c[2] = num[2] * (Q23 * Pf[3]);
    c[3] = num[3] * (Q23 * Pf[2]);
    float nh[4], Ph[4];
#pragma unroll
    for (int r = 0; r < 4; ++r) {
        const float D = __builtin_amdgcn_exp2f(acc[3][r]);   // e^-zo
        const float E = __builtin_amdgcn_exp2f(c[r] * SCALE_G);
        nh[r] = E - 1.0f;
        Ph[r] = (1.0f + D) * (E + 1.0f);
    }
    const float R01 = __builtin_amdgcn_rcpf(Ph[0] * Ph[1]);
    const float R23 = __builtin_amdgcn_rcpf(Ph[2] * Ph[3]);
    const float hh[4] = {nh[0] * (R01 * Ph[1]), nh[1] * (R01 * Ph[0]),
                         nh[2] * (R23 * Ph[3]), nh[3] * (R23 * Ph[2])};
#pragma unroll
    for (int r = 0; r < 4; ++r) {
        // truncation hi/lo split (err ~2^-17)
        const uint hu = __float_as_uint(hh[r]);
        const float hi_f = __uint_as_float(hu & 0xffff0000u);
        const float lo_f = hh[r] - hi_f;
        *(ushort*)(hn_hi + offW[r]) = (ushort)(hu >> 16);
        *(ushort*)(hn_lo + offW[r]) = (ushort)(__float_as_uint(lo_f) >> 16);
    }
}

__global__ __launch_bounds__(256, 1) void char_lstm_mfma(
    const int* __restrict__ chars,   // [N][25]
    const float* __restrict__ U,     // [64][256]
    const float* __restrict__ EWr,   // [128][64][4] permuted+scaled
    float* __restrict__ out)         // [N][64]
{
    const int j = threadIdx.x;
    const int w = j >> 6;            // wave 0..3
    const int l = j & 63;            // lane
    const int q = l >> 4;            // lane group 0..3
    const int n16 = l & 15;          // 0..15
    const int c16 = w * 16 + n16;    // this thread's unit/col-in-gate
    const int seq0 = blockIdx.x * SEQ_M;

    __shared__ int ibuf[TC_LEN + 1][SEQ_M];            // byte offsets, padded
    __shared__ ushort hbuf[2][2][2][16 * H_N];         // [buf][grp][plane], 16 KB

    // stage chars transposed as EWr BYTE offsets (row stride 1024)
    for (int idx = j; idx < TC_LEN * SEQ_M; idx += 256) {
        const int s = idx & 31, tt = idx >> 5;
        ibuf[tt][s] = chars[(seq0 + s) * TC_LEN + tt] << 10;
    }
    if (j < SEQ_M) ibuf[TC_LEN][j] = 0;                // dummy row: branchless
    // zero h buffer 0, both groups, both planes (4096 ushorts)
    {
        uint* z = (uint*)&hbuf[0][0][0][0];
        for (int idx = j; idx < 2048; idx += 256) z[idx] = 0u;
    }

    // ---- preload U fragments (pre-scaled, hi/lo), k-map k = ks*32+8q+e ----
    bf16x8 bh[4][2], bl[4][2];
#pragma unroll
    for (int tile = 0; tile < 4; ++tile) {
        const int colg = tile * 64 + c16;
        const float scale = (tile == 2) ? SCALE_G : SCALE_SIG;
#pragma unroll
        for (int ks = 0; ks < 2; ++ks) {
#pragma unroll
            for (int e = 0; e < 8; ++e) {
                const int k = ks * 32 + 8 * q + e;
                const float uv = U[k * G4_N + colg] * scale;
                const ushort hi = bf16_rne(uv);
                bh[tile][ks][e] = (short)hi;
                bl[tile][ks][e] = (short)bf16_rne(uv - bf16_tof(hi));
            }
        }
    }

    __syncthreads();

    // hoisted LDS offsets + pre-biased EWr byte base
    const int offA0 = hswz(n16, 16 * q);
    const int offA1 = hswz(n16, 64 + 16 * q);
    int offW[4];
#pragma unroll
    for (int r = 0; r < 4; ++r) offW[r] = hswz(4 * q + r, c16 * 2);
    const char* ewb = (const char*)EWr + c16 * 16;

    // ---- EWr rows for t=0, both groups ----
    f32x4 ewvA[4], ewvB[4];
    {
        const i32x4 cvA = *(const i32x4*)&ibuf[0][4 * q];
        const i32x4 cvB = *(const i32x4*)&ibuf[0][16 + 4 * q];
#pragma unroll
        for (int r = 0; r < 4; ++r) {
            ewvA[r] = *(const f32x4*)(ewb + cvA[r]);
            ewvB[r] = *(const f32x4*)(ewb + cvB[r]);
        }
    }

    float cA[4] = {0.0f, 0.0f, 0.0f, 0.0f};
    float cB[4] = {0.0f, 0.0f, 0.0f, 0.0f};
    int cur = 0;

    for (int t = 0; t < TC_LEN; ++t) {
        // acc init from prefetched EWr (scaled z from x-proj)
        f32x4 accA[4], accB[4];
#pragma unroll
        for (int tile = 0; tile < 4; ++tile) {
            accA[tile][0] = ewvA[0][tile]; accA[tile][1] = ewvA[1][tile];
            accA[tile][2] = ewvA[2][tile]; accA[tile][3] = ewvA[3][tile];
            accB[tile][0] = ewvB[0][tile]; accB[tile][1] = ewvB[1][tile];
            accB[tile][2] = ewvB[2][tile]; accB[tile][3] = ewvB[3][tile];
        }

        // A fragments for both groups (hi/lo planes of h)
        const char* base = (const char*)&hbuf[cur][0][0][0];
        const bf16x8 ahA0 = *(const bf16x8*)(base + offA0);
        const bf16x8 ahA1 = *(const bf16x8*)(base + offA1);
        const bf16x8 alA0 = *(const bf16x8*)(base + 2048 + offA0);
        const bf16x8 alA1 = *(const bf16x8*)(base + 2048 + offA1);
        const bf16x8 ahB0 = *(const bf16x8*)(base + 4096 + offA0);
        const bf16x8 ahB1 = *(const bf16x8*)(base + 4096 + offA1);
        const bf16x8 alB0 = *(const bf16x8*)(base + 6144 + offA0);
        const bf16x8 alB1 = *(const bf16x8*)(base + 6144 + offA1);

        // z += h.U : 3-term hi/lo split, 24 MFMA per group
#pragma unroll
        for (int tile = 0; tile < 4; ++tile) {
            accA[tile] = __builtin_amdgcn_mfma_f32_16x16x32_bf16(ahA0, bh[tile][0], accA[tile], 0, 0, 0);
            accA[tile] = __builtin_amdgcn_mfma_f32_16x16x32_bf16(ahA0, bl[tile][0], accA[tile], 0, 0, 0);
            accA[tile] = __builtin_amdgcn_mfma_f32_16x16x32_bf16(alA0, bh[tile][0], accA[tile], 0, 0, 0);
            accA[tile] = __builtin_amdgcn_mfma_f32_16x16x32_bf16(ahA1, bh[tile][1], accA[tile], 0, 0, 0);
            accA[tile] = __builtin_amdgcn_mfma_f32_16x16x32_bf16(ahA1, bl[tile][1], accA[tile], 0, 0, 0);
            accA[tile] = __builtin_amdgcn_mfma_f32_16x16x32_bf16(alA1, bh[tile][1], accA[tile], 0, 0, 0);
        }
#pragma unroll
        for (int tile = 0; tile < 4; ++tile) {
            accB[tile] = __builtin_amdgcn_mfma_f32_16x16x32_bf16(ahB0, bh[tile][0], accB[tile], 0, 0, 0);
            accB[tile] = __builtin_amdgcn_mfma_f32_16x16x32_bf16(ahB0, bl[tile][0], accB[tile], 0, 0, 0);
            accB[tile] = __builtin_amdgcn_mfma_f32_16x16x32_bf16(alB0, bh[tile][0], accB[tile], 0, 0, 0);
            accB[tile] = __builtin_amdgcn_mfma_f32_16x16x32_bf16(ahB1, bh[tile][1], accB[tile], 0, 0, 0);
            accB[tile] = __builtin_amdgcn_mfma_f32_16x16x32_bf16(ahB1, bl[tile][1], accB[tile], 0, 0, 0);
            accB[tile] = __builtin_amdgcn_mfma_f32_16x16x32_bf16(alB1, bh[tile][1], accB[tile], 0, 0, 0);
        }

        // prefetch next timestep's EWr rows (dummy row t=25 -> branchless)
        {
            const i32x4 cvA = *(const i32x4*)&ibuf[t + 1][4 * q];
            const i32x4 cvB = *(const i32x4*)&ibuf[t + 1][16 + 4 * q];
#pragma unroll
            for (int r = 0; r < 4; ++r) {
                ewvA[r] = *(const f32x4*)(ewb + cvA[r]);
                ewvB[r] = *(const f32x4*)(ewb + cvB[r]);
            }
        }

        // activations + h-writes; A and B chains independent -> interleave,
        // and B's MFMAs above overlap A's transcendental chain
        char* nbase = (char*)&hbuf[cur ^ 1][0][0][0];
        act_group(accA, cA, nbase,        nbase + 2048, offW);
        act_group(accB, cB, nbase + 4096, nbase + 6144, offW);

        __syncthreads();
        cur ^= 1;
    }

    // ---- write h_last: reconstruct from hbuf hi+lo (err ~2^-17) ----
    const char* fbase = (const char*)&hbuf[cur][0][0][0];
#pragma unroll
    for (int g = 0; g < 2; ++g) {
#pragma unroll
        for (int r = 0; r < 4; ++r) {
            const ushort hi = *(const ushort*)(fbase + g * 4096 + offW[r]);
            const ushort lo = *(const ushort*)(fbase + g * 4096 + 2048 + offW[r]);
            out[(seq0 + g * 16 + 4 * q + r) * H_N + c16] = bf16_tof(hi) + bf16_tof(lo);
        }
    }
}

extern "C" void kernel_launch(void* const* d_in, const int* in_sizes, int n_in,
                              void* d_out, int out_size, void* d_ws, size_t ws_size,
                              hipStream_t stream) {
    const int*   chars = (const int*)d_in[0];
    const float* E     = (const float*)d_in[1];
    const float* W     = (const float*)d_in[2];
    const float* U     = (const float*)d_in[3];
    const float* b     = (const float*)d_in[4];
    float* out = (float*)d_out;
    float* EWr = (float*)d_ws;                      // 131072 B

    const int N = in_sizes[0] / TC_LEN;             // 32768
    const int blocks = N / SEQ_M;                   // 1024

    ew_precompute<<<V_N, G4_N, 0, stream>>>(E, W, b, EWr);
    char_lstm_mfma<<<blocks, 256, 0, stream>>>(chars, U, EWr, out);
}

// Round 8
// 114.252 us; speedup vs baseline: 1.2809x; 1.2809x over previous
//
#include <hip/hip_runtime.h>
#include <hip/hip_bf16.h>

// CharLSTM: B=128, TW=256, TC=25, V=128, D=32, H=64 (4H=256), N=32768 seqs.
//
// R8 = R6 structure (SEQ_M=16, 2048 blocks — R7's 32-seq variant LOST
// cross-block TLP and regressed; reverted) with:
//  - U fragment table precomputed on device (u_pack kernel): bf16 hi/lo,
//    pre-scaled, fragment-major [col][plane][k] -> main kernel loads 16
//    dwordx4 (L2-hot) instead of 64 scattered loads + ~500 VALU cyc of
//    scale/rne per block.
//  - per-r independent merged rcp: c' = num * rcp(di*df*dg), h = nh *
//    rcp(do*dh). 8 rcp/lane-ts, 4 independent chains (R6's cross-r
//    pairing saved issue but lengthened the serial chain - net zero).
//  - s_setprio(1) around the MFMA cluster (T5: co-resident blocks at
//    different phases -> arbitration has role diversity).
//  - EWr prefetch issued BEFORE the MFMA cluster (covered by ~470 cyc
//    of MFMA pipe time).

#define SEQ_M 16
#define TC_LEN 25
#define H_N 64
#define D_N 32
#define G4_N 256
#define V_N 128

typedef __attribute__((ext_vector_type(8))) short bf16x8;
typedef __attribute__((ext_vector_type(4))) float f32x4;
typedef __attribute__((ext_vector_type(4))) int i32x4;

#define SCALE_SIG (-1.4426950408889634f)   /* -log2(e)  */
#define SCALE_G   ( 2.8853900817779268f)   /* 2*log2(e) */

__device__ __forceinline__ ushort bf16_rne(float x) {
    const uint u = __float_as_uint(x);
    return (ushort)((u + 0x7fffu + ((u >> 16) & 1u)) >> 16);
}
__device__ __forceinline__ float bf16_tof(ushort h) {
    return __uint_as_float(((uint)h) << 16);
}
// swizzled byte offset into a [16][64] bf16 (2 KB) tile
__device__ __forceinline__ int hswz(int row, int kbyte) {
    const int b = row * 128 + kbyte;
    return b ^ ((row & 7) << 4);
}

// ---- prologue 1: EWr[v][c16][tile] = ((E.W)[v][tile*64+c16]+b)*gate_scale ----
__global__ void ew_precompute(const float* __restrict__ E,
                              const float* __restrict__ W,
                              const float* __restrict__ b,
                              float* __restrict__ EWr) {
    const int v = blockIdx.x;
    const int j = threadIdx.x;           // output col = (j>>6)*64 + (j&63)
    float acc = b[j];
#pragma unroll
    for (int d = 0; d < D_N; ++d)
        acc = fmaf(E[v * D_N + d], W[d * G4_N + j], acc);
    const int tile = j >> 6, c16 = j & 63;
    const float scale = (tile == 2) ? SCALE_G : SCALE_SIG;
    EWr[v * G4_N + c16 * 4 + tile] = acc * scale;
}

// ---- prologue 2: Upk[col][plane][k] bf16, pre-scaled hi/lo split ----
__global__ void u_pack(const float* __restrict__ U, ushort* __restrict__ Upk) {
    const int k   = blockIdx.x;          // 0..63
    const int col = threadIdx.x;         // 0..255
    const float scale = ((col >> 6) == 2) ? SCALE_G : SCALE_SIG;
    const float uv = U[k * G4_N + col] * scale;
    const ushort hi = bf16_rne(uv);
    Upk[col * 128 + k]      = hi;
    Upk[col * 128 + 64 + k] = bf16_rne(uv - bf16_tof(hi));
}

__global__ __launch_bounds__(256, 1) void char_lstm_mfma(
    const int* __restrict__ chars,    // [N][25]
    const ushort* __restrict__ Upk,   // [256][2][64] bf16 frag table
    const float* __restrict__ EWr,    // [128][64][4] permuted+scaled
    float* __restrict__ out)          // [N][64]
{
    const int j = threadIdx.x;
    const int w = j >> 6;            // wave 0..3
    const int l = j & 63;            // lane
    const int q = l >> 4;            // lane group 0..3
    const int n16 = l & 15;          // 0..15
    const int c16 = w * 16 + n16;    // this thread's unit/col-in-gate
    const int seq0 = blockIdx.x * SEQ_M;

    __shared__ int ibuf[TC_LEN + 1][SEQ_M];          // byte offsets, padded
    __shared__ ushort hbuf[2][2][SEQ_M * H_N];       // [buf][hi/lo], 8 KB

    // stage chars transposed as EWr BYTE offsets (row stride 256*4 = 1024)
    for (int idx = j; idx < TC_LEN * SEQ_M; idx += 256) {
        const int s = idx & 15, tt = idx >> 4;
        ibuf[tt][s] = chars[(seq0 + s) * TC_LEN + tt] << 10;
    }
    if (j < SEQ_M) ibuf[TC_LEN][j] = 0;              // dummy row: branchless
    // zero h buffer 0 (hi+lo planes)
    {
        uint* z = (uint*)&hbuf[0][0][0];
        for (int idx = j; idx < 1024; idx += 256) z[idx] = 0u;
    }

    // ---- load pre-packed U fragments: 16x dwordx4, L2-hot ----
    bf16x8 bh[4][2], bl[4][2];
#pragma unroll
    for (int tile = 0; tile < 4; ++tile) {
        const ushort* ub = Upk + (tile * 64 + c16) * 128 + 8 * q;
#pragma unroll
        for (int ks = 0; ks < 2; ++ks) {
            bh[tile][ks] = *(const bf16x8*)(ub + ks * 32);
            bl[tile][ks] = *(const bf16x8*)(ub + 64 + ks * 32);
        }
    }

    __syncthreads();

    // hoisted LDS offsets + pre-biased EWr byte base
    const int offA0 = hswz(n16, 16 * q);
    const int offA1 = hswz(n16, 64 + 16 * q);
    int offW[4];
#pragma unroll
    for (int r = 0; r < 4; ++r) offW[r] = hswz(4 * q + r, c16 * 2);
    const char* ewb = (const char*)EWr + c16 * 16;

    // ---- EWr rows for t=0 ----
    f32x4 ewv[4];
    {
        const i32x4 cv = *(const i32x4*)&ibuf[0][4 * q];
#pragma unroll
        for (int r = 0; r < 4; ++r)
            ewv[r] = *(const f32x4*)(ewb + cv[r]);
    }

    float c[4] = {0.0f, 0.0f, 0.0f, 0.0f};
    int cur = 0;

    for (int t = 0; t < TC_LEN; ++t) {
        // acc init: acc[tile][r] = ewv[r][tile]  (scaled z from x-proj)
        f32x4 acc[4];
#pragma unroll
        for (int tile = 0; tile < 4; ++tile) {
            acc[tile][0] = ewv[0][tile];
            acc[tile][1] = ewv[1][tile];
            acc[tile][2] = ewv[2][tile];
            acc[tile][3] = ewv[3][tile];
        }

        // A fragments (hi/lo planes of h)
        const char* hb_hi = (const char*)&hbuf[cur][0][0];
        const char* hb_lo = (const char*)&hbuf[cur][1][0];
        const bf16x8 ah0 = *(const bf16x8*)(hb_hi + offA0);
        const bf16x8 ah1 = *(const bf16x8*)(hb_hi + offA1);
        const bf16x8 al0 = *(const bf16x8*)(hb_lo + offA0);
        const bf16x8 al1 = *(const bf16x8*)(hb_lo + offA1);

        // prefetch next timestep's EWr rows early (covered by MFMA cluster;
        // dummy row t=25 -> branchless)
        {
            const i32x4 cv = *(const i32x4*)&ibuf[t + 1][4 * q];
#pragma unroll
            for (int r = 0; r < 4; ++r)
                ewv[r] = *(const f32x4*)(ewb + cv[r]);
        }

        // z += h.U : 3-term hi/lo split, 24 MFMA
        __builtin_amdgcn_s_setprio(1);
#pragma unroll
        for (int tile = 0; tile < 4; ++tile) {
            acc[tile] = __builtin_amdgcn_mfma_f32_16x16x32_bf16(ah0, bh[tile][0], acc[tile], 0, 0, 0);
            acc[tile] = __builtin_amdgcn_mfma_f32_16x16x32_bf16(ah0, bl[tile][0], acc[tile], 0, 0, 0);
            acc[tile] = __builtin_amdgcn_mfma_f32_16x16x32_bf16(al0, bh[tile][0], acc[tile], 0, 0, 0);
            acc[tile] = __builtin_amdgcn_mfma_f32_16x16x32_bf16(ah1, bh[tile][1], acc[tile], 0, 0, 0);
            acc[tile] = __builtin_amdgcn_mfma_f32_16x16x32_bf16(ah1, bl[tile][1], acc[tile], 0, 0, 0);
            acc[tile] = __builtin_amdgcn_mfma_f32_16x16x32_bf16(al1, bh[tile][1], acc[tile], 0, 0, 0);
        }
        __builtin_amdgcn_s_setprio(0);

        // ---- activations; acc pre-scaled -> exp2 directly.
        // per-r independent chains, one rcp per family:
        //   c' = (c*di*dg + ng*df) * rcp(di*df*dg);  h = nh * rcp(do*dh)
        char* hn_hi = (char*)&hbuf[cur ^ 1][0][0];
        char* hn_lo = (char*)&hbuf[cur ^ 1][1][0];
#pragma unroll
        for (int r = 0; r < 4; ++r) {
            const float A = __builtin_amdgcn_exp2f(acc[0][r]);   // e^-zi
            const float B = __builtin_amdgcn_exp2f(acc[1][r]);   // e^-zf
            const float C = __builtin_amdgcn_exp2f(acc[2][r]);   // e^2zg
            const float di = 1.0f + A, df = 1.0f + B, dg = 1.0f + C;
            const float m1 = di * dg;
            const float num = fmaf(c[r], m1, (C - 1.0f) * df);
            c[r] = num * __builtin_amdgcn_rcpf(m1 * df);
            const float D  = __builtin_amdgcn_exp2f(acc[3][r]);  // e^-zo
            const float E2 = __builtin_amdgcn_exp2f(c[r] * SCALE_G);
            const float nh = E2 - 1.0f;
            const float Ph = (1.0f + D) * (E2 + 1.0f);
            const float h = nh * __builtin_amdgcn_rcpf(Ph);      // o*tanh(c')
            // truncation hi/lo split (err ~2^-17)
            const uint hu = __float_as_uint(h);
            const float hi_f = __uint_as_float(hu & 0xffff0000u);
            const float lo_f = h - hi_f;
            *(ushort*)(hn_hi + offW[r]) = (ushort)(hu >> 16);
            *(ushort*)(hn_lo + offW[r]) = (ushort)(__float_as_uint(lo_f) >> 16);
        }
        __syncthreads();
        cur ^= 1;
    }

    // ---- write h_last: reconstruct from hbuf hi+lo (err ~2^-17) ----
    const char* hf_hi = (const char*)&hbuf[cur][0][0];
    const char* hf_lo = (const char*)&hbuf[cur][1][0];
#pragma unroll
    for (int r = 0; r < 4; ++r) {
        const ushort hi = *(const ushort*)(hf_hi + offW[r]);
        const ushort lo = *(const ushort*)(hf_lo + offW[r]);
        out[(seq0 + 4 * q + r) * H_N + c16] = bf16_tof(hi) + bf16_tof(lo);
    }
}

extern "C" void kernel_launch(void* const* d_in, const int* in_sizes, int n_in,
                              void* d_out, int out_size, void* d_ws, size_t ws_size,
                              hipStream_t stream) {
    const int*   chars = (const int*)d_in[0];
    const float* E     = (const float*)d_in[1];
    const float* W     = (const float*)d_in[2];
    const float* U     = (const float*)d_in[3];
    const float* b     = (const float*)d_in[4];
    float* out = (float*)d_out;
    float*  EWr = (float*)d_ws;                         // 131072 B
    ushort* Upk = (ushort*)((char*)d_ws + 131072);      // 65536 B

    const int N = in_sizes[0] / TC_LEN;             // 32768
    const int blocks = N / SEQ_M;                   // 2048

    ew_precompute<<<V_N, G4_N, 0, stream>>>(E, W, b, EWr);
    u_pack<<<H_N, G4_N, 0, stream>>>(U, Upk);
    char_lstm_mfma<<<blocks, 256, 0, stream>>>(chars, Upk, EWr, out);
}

// Round 9
// 106.353 us; speedup vs baseline: 1.3761x; 1.0743x over previous
//
#include <hip/hip_runtime.h>
#include <hip/hip_bf16.h>

// CharLSTM: B=128, TW=256, TC=25, V=128, D=32, H=64 (4H=256), N=32768 seqs.
//
// R9 = R8 + occupancy-cliff fix:
//  - Combined VGPR+AGPR demand in R8 was ~130, just above the 128-reg
//    tier (>128 -> 2 waves/SIMD -> 2 blocks/CU; barrier-lockstep waves
//    stall together -> ~40% issue-idle). __launch_bounds__(256,4) caps
//    at 128; k-half A-fragment split (-8 live regs) makes it fit.
//  - MFMA cluster reordered TERM-MAJOR (hh x4 tiles, hl x4, lh x4 per
//    k-half): same-accumulator MFMAs now 4 apart, not 6-deep chains.
//  - Tripwire: if FETCH/WRITE balloons, the bound forced spills.

#define SEQ_M 16
#define TC_LEN 25
#define H_N 64
#define D_N 32
#define G4_N 256
#define V_N 128

typedef __attribute__((ext_vector_type(8))) short bf16x8;
typedef __attribute__((ext_vector_type(4))) float f32x4;
typedef __attribute__((ext_vector_type(4))) int i32x4;

#define SCALE_SIG (-1.4426950408889634f)   /* -log2(e)  */
#define SCALE_G   ( 2.8853900817779268f)   /* 2*log2(e) */

__device__ __forceinline__ ushort bf16_rne(float x) {
    const uint u = __float_as_uint(x);
    return (ushort)((u + 0x7fffu + ((u >> 16) & 1u)) >> 16);
}
__device__ __forceinline__ float bf16_tof(ushort h) {
    return __uint_as_float(((uint)h) << 16);
}
// swizzled byte offset into a [16][64] bf16 (2 KB) tile
__device__ __forceinline__ int hswz(int row, int kbyte) {
    const int b = row * 128 + kbyte;
    return b ^ ((row & 7) << 4);
}

// ---- prologue 1: EWr[v][c16][tile] = ((E.W)[v][tile*64+c16]+b)*gate_scale ----
__global__ void ew_precompute(const float* __restrict__ E,
                              const float* __restrict__ W,
                              const float* __restrict__ b,
                              float* __restrict__ EWr) {
    const int v = blockIdx.x;
    const int j = threadIdx.x;           // output col = (j>>6)*64 + (j&63)
    float acc = b[j];
#pragma unroll
    for (int d = 0; d < D_N; ++d)
        acc = fmaf(E[v * D_N + d], W[d * G4_N + j], acc);
    const int tile = j >> 6, c16 = j & 63;
    const float scale = (tile == 2) ? SCALE_G : SCALE_SIG;
    EWr[v * G4_N + c16 * 4 + tile] = acc * scale;
}

// ---- prologue 2: Upk[col][plane][k] bf16, pre-scaled hi/lo split ----
__global__ void u_pack(const float* __restrict__ U, ushort* __restrict__ Upk) {
    const int k   = blockIdx.x;          // 0..63
    const int col = threadIdx.x;         // 0..255
    const float scale = ((col >> 6) == 2) ? SCALE_G : SCALE_SIG;
    const float uv = U[k * G4_N + col] * scale;
    const ushort hi = bf16_rne(uv);
    Upk[col * 128 + k]      = hi;
    Upk[col * 128 + 64 + k] = bf16_rne(uv - bf16_tof(hi));
}

__global__ __launch_bounds__(256, 4) void char_lstm_mfma(
    const int* __restrict__ chars,    // [N][25]
    const ushort* __restrict__ Upk,   // [256][2][64] bf16 frag table
    const float* __restrict__ EWr,    // [128][64][4] permuted+scaled
    float* __restrict__ out)          // [N][64]
{
    const int j = threadIdx.x;
    const int w = j >> 6;            // wave 0..3
    const int l = j & 63;            // lane
    const int q = l >> 4;            // lane group 0..3
    const int n16 = l & 15;          // 0..15
    const int c16 = w * 16 + n16;    // this thread's unit/col-in-gate
    const int seq0 = blockIdx.x * SEQ_M;

    __shared__ int ibuf[TC_LEN + 1][SEQ_M];          // byte offsets, padded
    __shared__ ushort hbuf[2][2][SEQ_M * H_N];       // [buf][hi/lo], 8 KB

    // stage chars transposed as EWr BYTE offsets (row stride 256*4 = 1024)
    for (int idx = j; idx < TC_LEN * SEQ_M; idx += 256) {
        const int s = idx & 15, tt = idx >> 4;
        ibuf[tt][s] = chars[(seq0 + s) * TC_LEN + tt] << 10;
    }
    if (j < SEQ_M) ibuf[TC_LEN][j] = 0;              // dummy row: branchless
    // zero h buffer 0 (hi+lo planes)
    {
        uint* z = (uint*)&hbuf[0][0][0];
        for (int idx = j; idx < 1024; idx += 256) z[idx] = 0u;
    }

    // ---- load pre-packed U fragments: 16x dwordx4, L2-hot ----
    bf16x8 bh[4][2], bl[4][2];
#pragma unroll
    for (int tile = 0; tile < 4; ++tile) {
        const ushort* ub = Upk + (tile * 64 + c16) * 128 + 8 * q;
#pragma unroll
        for (int ks = 0; ks < 2; ++ks) {
            bh[tile][ks] = *(const bf16x8*)(ub + ks * 32);
            bl[tile][ks] = *(const bf16x8*)(ub + 64 + ks * 32);
        }
    }

    __syncthreads();

    // hoisted LDS offsets + pre-biased EWr byte base
    const int offA0 = hswz(n16, 16 * q);
    const int offA1 = hswz(n16, 64 + 16 * q);
    int offW[4];
#pragma unroll
    for (int r = 0; r < 4; ++r) offW[r] = hswz(4 * q + r, c16 * 2);
    const char* ewb = (const char*)EWr + c16 * 16;

    // ---- EWr rows for t=0 ----
    f32x4 ewv[4];
    {
        const i32x4 cv = *(const i32x4*)&ibuf[0][4 * q];
#pragma unroll
        for (int r = 0; r < 4; ++r)
            ewv[r] = *(const f32x4*)(ewb + cv[r]);
    }

    float c[4] = {0.0f, 0.0f, 0.0f, 0.0f};
    int cur = 0;

    for (int t = 0; t < TC_LEN; ++t) {
        // acc init: acc[tile][r] = ewv[r][tile]  (scaled z from x-proj)
        f32x4 acc[4];
#pragma unroll
        for (int tile = 0; tile < 4; ++tile) {
            acc[tile][0] = ewv[0][tile];
            acc[tile][1] = ewv[1][tile];
            acc[tile][2] = ewv[2][tile];
            acc[tile][3] = ewv[3][tile];
        }

        const char* hb_hi = (const char*)&hbuf[cur][0][0];
        const char* hb_lo = (const char*)&hbuf[cur][1][0];

        // prefetch next timestep's EWr rows early (covered by MFMA cluster;
        // dummy row t=25 -> branchless)
        {
            const i32x4 cv = *(const i32x4*)&ibuf[t + 1][4 * q];
#pragma unroll
            for (int r = 0; r < 4; ++r)
                ewv[r] = *(const f32x4*)(ewb + cv[r]);
        }

        __builtin_amdgcn_s_setprio(1);
        // ---- k-half 0: only ah0/al0 live (8 regs); term-major order ----
        {
            const bf16x8 ah0 = *(const bf16x8*)(hb_hi + offA0);
            const bf16x8 al0 = *(const bf16x8*)(hb_lo + offA0);
#pragma unroll
            for (int tile = 0; tile < 4; ++tile)
                acc[tile] = __builtin_amdgcn_mfma_f32_16x16x32_bf16(ah0, bh[tile][0], acc[tile], 0, 0, 0);
#pragma unroll
            for (int tile = 0; tile < 4; ++tile)
                acc[tile] = __builtin_amdgcn_mfma_f32_16x16x32_bf16(ah0, bl[tile][0], acc[tile], 0, 0, 0);
#pragma unroll
            for (int tile = 0; tile < 4; ++tile)
                acc[tile] = __builtin_amdgcn_mfma_f32_16x16x32_bf16(al0, bh[tile][0], acc[tile], 0, 0, 0);
        }
        // ---- k-half 1 ----
        {
            const bf16x8 ah1 = *(const bf16x8*)(hb_hi + offA1);
            const bf16x8 al1 = *(const bf16x8*)(hb_lo + offA1);
#pragma unroll
            for (int tile = 0; tile < 4; ++tile)
                acc[tile] = __builtin_amdgcn_mfma_f32_16x16x32_bf16(ah1, bh[tile][1], acc[tile], 0, 0, 0);
#pragma unroll
            for (int tile = 0; tile < 4; ++tile)
                acc[tile] = __builtin_amdgcn_mfma_f32_16x16x32_bf16(ah1, bl[tile][1], acc[tile], 0, 0, 0);
#pragma unroll
            for (int tile = 0; tile < 4; ++tile)
                acc[tile] = __builtin_amdgcn_mfma_f32_16x16x32_bf16(al1, bh[tile][1], acc[tile], 0, 0, 0);
        }
        __builtin_amdgcn_s_setprio(0);

        // ---- activations; acc pre-scaled -> exp2 directly.
        // per-r independent chains, one rcp per family:
        //   c' = (c*di*dg + ng*df) * rcp(di*df*dg);  h = nh * rcp(do*dh)
        char* hn_hi = (char*)&hbuf[cur ^ 1][0][0];
        char* hn_lo = (char*)&hbuf[cur ^ 1][1][0];
#pragma unroll
        for (int r = 0; r < 4; ++r) {
            const float A = __builtin_amdgcn_exp2f(acc[0][r]);   // e^-zi
            const float B = __builtin_amdgcn_exp2f(acc[1][r]);   // e^-zf
            const float C = __builtin_amdgcn_exp2f(acc[2][r]);   // e^2zg
            const float di = 1.0f + A, df = 1.0f + B, dg = 1.0f + C;
            const float m1 = di * dg;
            const float num = fmaf(c[r], m1, (C - 1.0f) * df);
            c[r] = num * __builtin_amdgcn_rcpf(m1 * df);
            const float D  = __builtin_amdgcn_exp2f(acc[3][r]);  // e^-zo
            const float E2 = __builtin_amdgcn_exp2f(c[r] * SCALE_G);
            const float nh = E2 - 1.0f;
            const float Ph = (1.0f + D) * (E2 + 1.0f);
            const float h = nh * __builtin_amdgcn_rcpf(Ph);      // o*tanh(c')
            // truncation hi/lo split (err ~2^-17)
            const uint hu = __float_as_uint(h);
            const float hi_f = __uint_as_float(hu & 0xffff0000u);
            const float lo_f = h - hi_f;
            *(ushort*)(hn_hi + offW[r]) = (ushort)(hu >> 16);
            *(ushort*)(hn_lo + offW[r]) = (ushort)(__float_as_uint(lo_f) >> 16);
        }
        __syncthreads();
        cur ^= 1;
    }

    // ---- write h_last: reconstruct from hbuf hi+lo (err ~2^-17) ----
    const char* hf_hi = (const char*)&hbuf[cur][0][0];
    const char* hf_lo = (const char*)&hbuf[cur][1][0];
#pragma unroll
    for (int r = 0; r < 4; ++r) {
        const ushort hi = *(const ushort*)(hf_hi + offW[r]);
        const ushort lo = *(const ushort*)(hf_lo + offW[r]);
        out[(seq0 + 4 * q + r) * H_N + c16] = bf16_tof(hi) + bf16_tof(lo);
    }
}

extern "C" void kernel_launch(void* const* d_in, const int* in_sizes, int n_in,
                              void* d_out, int out_size, void* d_ws, size_t ws_size,
                              hipStream_t stream) {
    const int*   chars = (const int*)d_in[0];
    const float* E     = (const float*)d_in[1];
    const float* W     = (const float*)d_in[2];
    const float* U     = (const float*)d_in[3];
    const float* b     = (const float*)d_in[4];
    float* out = (float*)d_out;
    float*  EWr = (float*)d_ws;                         // 131072 B
    ushort* Upk = (ushort*)((char*)d_ws + 131072);      // 65536 B

    const int N = in_sizes[0] / TC_LEN;             // 32768
    const int blocks = N / SEQ_M;                   // 2048

    ew_precompute<<<V_N, G4_N, 0, stream>>>(E, W, b, EWr);
    u_pack<<<H_N, G4_N, 0, stream>>>(U, Upk);
    char_lstm_mfma<<<blocks, 256, 0, stream>>>(chars, Upk, EWr, out);
}

// Round 10
// 90.933 us; speedup vs baseline: 1.6094x; 1.1696x over previous
//
#include <hip/hip_runtime.h>
#include <hip/hip_bf16.h>

// CharLSTM: B=128, TW=256, TC=25, V=128, D=32, H=64 (4H=256), N=32768 seqs.
//
// R10 = R9 with the U-lo MFMA term dropped (2-term split: ah*bh + al*bh):
//  - h keeps hi/lo bf16 precision (recurrence-critical); U is bf16-hi only
//    (static operand, zero-mean rounding error across the K=64 reduction;
//    predicted +~1e-4 RMS output error, threshold 1.8e-3, current 4.9e-4).
//  - Frees bl[4][2] = 32 persistent regs -> total ~100, inside the
//    128-reg 4-waves/SIMD tier (R9 stalled at 2.8 waves: hidden AGPRs).
//  - MFMA 24 -> 16 per wave-timestep (-33% matrix pipe).
//  Fallback if absmax fails: U-lo term with bl staged in LDS (no regs).

#define SEQ_M 16
#define TC_LEN 25
#define H_N 64
#define D_N 32
#define G4_N 256
#define V_N 128

typedef __attribute__((ext_vector_type(8))) short bf16x8;
typedef __attribute__((ext_vector_type(4))) float f32x4;
typedef __attribute__((ext_vector_type(4))) int i32x4;

#define SCALE_SIG (-1.4426950408889634f)   /* -log2(e)  */
#define SCALE_G   ( 2.8853900817779268f)   /* 2*log2(e) */

__device__ __forceinline__ ushort bf16_rne(float x) {
    const uint u = __float_as_uint(x);
    return (ushort)((u + 0x7fffu + ((u >> 16) & 1u)) >> 16);
}
__device__ __forceinline__ float bf16_tof(ushort h) {
    return __uint_as_float(((uint)h) << 16);
}
// swizzled byte offset into a [16][64] bf16 (2 KB) tile
__device__ __forceinline__ int hswz(int row, int kbyte) {
    const int b = row * 128 + kbyte;
    return b ^ ((row & 7) << 4);
}

// ---- prologue 1: EWr[v][c16][tile] = ((E.W)[v][tile*64+c16]+b)*gate_scale ----
__global__ void ew_precompute(const float* __restrict__ E,
                              const float* __restrict__ W,
                              const float* __restrict__ b,
                              float* __restrict__ EWr) {
    const int v = blockIdx.x;
    const int j = threadIdx.x;           // output col = (j>>6)*64 + (j&63)
    float acc = b[j];
#pragma unroll
    for (int d = 0; d < D_N; ++d)
        acc = fmaf(E[v * D_N + d], W[d * G4_N + j], acc);
    const int tile = j >> 6, c16 = j & 63;
    const float scale = (tile == 2) ? SCALE_G : SCALE_SIG;
    EWr[v * G4_N + c16 * 4 + tile] = acc * scale;
}

// ---- prologue 2: Upk[col][k] bf16-hi, pre-scaled ----
__global__ void u_pack(const float* __restrict__ U, ushort* __restrict__ Upk) {
    const int k   = blockIdx.x;          // 0..63
    const int col = threadIdx.x;         // 0..255
    const float scale = ((col >> 6) == 2) ? SCALE_G : SCALE_SIG;
    const float uv = U[k * G4_N + col] * scale;
    Upk[col * 64 + k] = bf16_rne(uv);
}

__global__ __launch_bounds__(256, 4) void char_lstm_mfma(
    const int* __restrict__ chars,    // [N][25]
    const ushort* __restrict__ Upk,   // [256][64] bf16-hi frag table
    const float* __restrict__ EWr,    // [128][64][4] permuted+scaled
    float* __restrict__ out)          // [N][64]
{
    const int j = threadIdx.x;
    const int w = j >> 6;            // wave 0..3
    const int l = j & 63;            // lane
    const int q = l >> 4;            // lane group 0..3
    const int n16 = l & 15;          // 0..15
    const int c16 = w * 16 + n16;    // this thread's unit/col-in-gate
    const int seq0 = blockIdx.x * SEQ_M;

    __shared__ int ibuf[TC_LEN + 1][SEQ_M];          // byte offsets, padded
    __shared__ ushort hbuf[2][2][SEQ_M * H_N];       // [buf][hi/lo], 8 KB

    // stage chars transposed as EWr BYTE offsets (row stride 256*4 = 1024)
    for (int idx = j; idx < TC_LEN * SEQ_M; idx += 256) {
        const int s = idx & 15, tt = idx >> 4;
        ibuf[tt][s] = chars[(seq0 + s) * TC_LEN + tt] << 10;
    }
    if (j < SEQ_M) ibuf[TC_LEN][j] = 0;              // dummy row: branchless
    // zero h buffer 0 (hi+lo planes)
    {
        uint* z = (uint*)&hbuf[0][0][0];
        for (int idx = j; idx < 1024; idx += 256) z[idx] = 0u;
    }

    // ---- load pre-packed U-hi fragments: 8x dwordx4, L2-hot ----
    bf16x8 bh[4][2];
#pragma unroll
    for (int tile = 0; tile < 4; ++tile) {
        const ushort* ub = Upk + (tile * 64 + c16) * 64 + 8 * q;
#pragma unroll
        for (int ks = 0; ks < 2; ++ks)
            bh[tile][ks] = *(const bf16x8*)(ub + ks * 32);
    }

    __syncthreads();

    // hoisted LDS offsets + pre-biased EWr byte base
    const int offA0 = hswz(n16, 16 * q);
    const int offA1 = hswz(n16, 64 + 16 * q);
    int offW[4];
#pragma unroll
    for (int r = 0; r < 4; ++r) offW[r] = hswz(4 * q + r, c16 * 2);
    const char* ewb = (const char*)EWr + c16 * 16;

    // ---- EWr rows for t=0 ----
    f32x4 ewv[4];
    {
        const i32x4 cv = *(const i32x4*)&ibuf[0][4 * q];
#pragma unroll
        for (int r = 0; r < 4; ++r)
            ewv[r] = *(const f32x4*)(ewb + cv[r]);
    }

    float c[4] = {0.0f, 0.0f, 0.0f, 0.0f};
    int cur = 0;

    for (int t = 0; t < TC_LEN; ++t) {
        // acc init: acc[tile][r] = ewv[r][tile]  (scaled z from x-proj)
        f32x4 acc[4];
#pragma unroll
        for (int tile = 0; tile < 4; ++tile) {
            acc[tile][0] = ewv[0][tile];
            acc[tile][1] = ewv[1][tile];
            acc[tile][2] = ewv[2][tile];
            acc[tile][3] = ewv[3][tile];
        }

        const char* hb_hi = (const char*)&hbuf[cur][0][0];
        const char* hb_lo = (const char*)&hbuf[cur][1][0];

        // prefetch next timestep's EWr rows early (covered by MFMA cluster;
        // dummy row t=25 -> branchless)
        {
            const i32x4 cv = *(const i32x4*)&ibuf[t + 1][4 * q];
#pragma unroll
            for (int r = 0; r < 4; ++r)
                ewv[r] = *(const f32x4*)(ewb + cv[r]);
        }

        __builtin_amdgcn_s_setprio(1);
        // ---- k-half 0: term-major, 8 MFMA ----
        {
            const bf16x8 ah0 = *(const bf16x8*)(hb_hi + offA0);
            const bf16x8 al0 = *(const bf16x8*)(hb_lo + offA0);
#pragma unroll
            for (int tile = 0; tile < 4; ++tile)
                acc[tile] = __builtin_amdgcn_mfma_f32_16x16x32_bf16(ah0, bh[tile][0], acc[tile], 0, 0, 0);
#pragma unroll
            for (int tile = 0; tile < 4; ++tile)
                acc[tile] = __builtin_amdgcn_mfma_f32_16x16x32_bf16(al0, bh[tile][0], acc[tile], 0, 0, 0);
        }
        // ---- k-half 1 ----
        {
            const bf16x8 ah1 = *(const bf16x8*)(hb_hi + offA1);
            const bf16x8 al1 = *(const bf16x8*)(hb_lo + offA1);
#pragma unroll
            for (int tile = 0; tile < 4; ++tile)
                acc[tile] = __builtin_amdgcn_mfma_f32_16x16x32_bf16(ah1, bh[tile][1], acc[tile], 0, 0, 0);
#pragma unroll
            for (int tile = 0; tile < 4; ++tile)
                acc[tile] = __builtin_amdgcn_mfma_f32_16x16x32_bf16(al1, bh[tile][1], acc[tile], 0, 0, 0);
        }
        __builtin_amdgcn_s_setprio(0);

        // ---- activations; acc pre-scaled -> exp2 directly.
        // per-r independent chains, one rcp per family:
        //   c' = (c*di*dg + ng*df) * rcp(di*df*dg);  h = nh * rcp(do*dh)
        char* hn_hi = (char*)&hbuf[cur ^ 1][0][0];
        char* hn_lo = (char*)&hbuf[cur ^ 1][1][0];
#pragma unroll
        for (int r = 0; r < 4; ++r) {
            const float A = __builtin_amdgcn_exp2f(acc[0][r]);   // e^-zi
            const float B = __builtin_amdgcn_exp2f(acc[1][r]);   // e^-zf
            const float C = __builtin_amdgcn_exp2f(acc[2][r]);   // e^2zg
            const float di = 1.0f + A, df = 1.0f + B, dg = 1.0f + C;
            const float m1 = di * dg;
            const float num = fmaf(c[r], m1, (C - 1.0f) * df);
            c[r] = num * __builtin_amdgcn_rcpf(m1 * df);
            const float D  = __builtin_amdgcn_exp2f(acc[3][r]);  // e^-zo
            const float E2 = __builtin_amdgcn_exp2f(c[r] * SCALE_G);
            const float nh = E2 - 1.0f;
            const float Ph = (1.0f + D) * (E2 + 1.0f);
            const float h = nh * __builtin_amdgcn_rcpf(Ph);      // o*tanh(c')
            // truncation hi/lo split (err ~2^-17)
            const uint hu = __float_as_uint(h);
            const float hi_f = __uint_as_float(hu & 0xffff0000u);
            const float lo_f = h - hi_f;
            *(ushort*)(hn_hi + offW[r]) = (ushort)(hu >> 16);
            *(ushort*)(hn_lo + offW[r]) = (ushort)(__float_as_uint(lo_f) >> 16);
        }
        __syncthreads();
        cur ^= 1;
    }

    // ---- write h_last: reconstruct from hbuf hi+lo (err ~2^-17) ----
    const char* hf_hi = (const char*)&hbuf[cur][0][0];
    const char* hf_lo = (const char*)&hbuf[cur][1][0];
#pragma unroll
    for (int r = 0; r < 4; ++r) {
        const ushort hi = *(const ushort*)(hf_hi + offW[r]);
        const ushort lo = *(const ushort*)(hf_lo + offW[r]);
        out[(seq0 + 4 * q + r) * H_N + c16] = bf16_tof(hi) + bf16_tof(lo);
    }
}

extern "C" void kernel_launch(void* const* d_in, const int* in_sizes, int n_in,
                              void* d_out, int out_size, void* d_ws, size_t ws_size,
                              hipStream_t stream) {
    const int*   chars = (const int*)d_in[0];
    const float* E     = (const float*)d_in[1];
    const float* W     = (const float*)d_in[2];
    const float* U     = (const float*)d_in[3];
    const float* b     = (const float*)d_in[4];
    float* out = (float*)d_out;
    float*  EWr = (float*)d_ws;                         // 131072 B
    ushort* Upk = (ushort*)((char*)d_ws + 131072);      // 32768 B

    const int N = in_sizes[0] / TC_LEN;             // 32768
    const int blocks = N / SEQ_M;                   // 2048

    ew_precompute<<<V_N, G4_N, 0, stream>>>(E, W, b, EWr);
    u_pack<<<H_N, G4_N, 0, stream>>>(U, Upk);
    char_lstm_mfma<<<blocks, 256, 0, stream>>>(chars, Upk, EWr, out);
}

// Round 11
// 87.796 us; speedup vs baseline: 1.6669x; 1.0357x over previous
//
#include <hip/hip_runtime.h>
#include <hip/hip_bf16.h>

// CharLSTM: B=128, TW=256, TC=25, V=128, D=32, H=64 (4H=256), N=32768 seqs.
//
// R11 = R10 + structural edge-trims (occupancy is tier-capped at 4
// waves/SIMD; R6 showed instr-count cuts alone are neutral; so: cut the
// dead cycles at loop edges):
//  - t=0 peeled: h0=0 -> no hbuf zero-fill, no A-frag reads, no MFMA.
//  - t=24 peeled: h written straight to global from registers (no LDS
//    write, no final barrier, no epilogue re-read).
//  - 2x unrolled main loop with compile-time buffer parity (no cur^=1).
//  - All 4 exp2 args per cell issued together (D hoisted into phase 1).

#define SEQ_M 16
#define TC_LEN 25
#define H_N 64
#define D_N 32
#define G4_N 256
#define V_N 128

typedef __attribute__((ext_vector_type(8))) short bf16x8;
typedef __attribute__((ext_vector_type(4))) float f32x4;
typedef __attribute__((ext_vector_type(4))) int i32x4;

#define SCALE_SIG (-1.4426950408889634f)   /* -log2(e)  */
#define SCALE_G   ( 2.8853900817779268f)   /* 2*log2(e) */

__device__ __forceinline__ ushort bf16_rne(float x) {
    const uint u = __float_as_uint(x);
    return (ushort)((u + 0x7fffu + ((u >> 16) & 1u)) >> 16);
}
__device__ __forceinline__ float bf16_tof(ushort h) {
    return __uint_as_float(((uint)h) << 16);
}
// swizzled byte offset into a [16][64] bf16 (2 KB) tile
__device__ __forceinline__ int hswz(int row, int kbyte) {
    const int b = row * 128 + kbyte;
    return b ^ ((row & 7) << 4);
}

// ---- prologue 1: EWr[v][c16][tile] = ((E.W)[v][tile*64+c16]+b)*gate_scale ----
__global__ void ew_precompute(const float* __restrict__ E,
                              const float* __restrict__ W,
                              const float* __restrict__ b,
                              float* __restrict__ EWr) {
    const int v = blockIdx.x;
    const int j = threadIdx.x;           // output col = (j>>6)*64 + (j&63)
    float acc = b[j];
#pragma unroll
    for (int d = 0; d < D_N; ++d)
        acc = fmaf(E[v * D_N + d], W[d * G4_N + j], acc);
    const int tile = j >> 6, c16 = j & 63;
    const float scale = (tile == 2) ? SCALE_G : SCALE_SIG;
    EWr[v * G4_N + c16 * 4 + tile] = acc * scale;
}

// ---- prologue 2: Upk[col][k] bf16-hi, pre-scaled ----
__global__ void u_pack(const float* __restrict__ U, ushort* __restrict__ Upk) {
    const int k   = blockIdx.x;          // 0..63
    const int col = threadIdx.x;         // 0..255
    const float scale = ((col >> 6) == 2) ? SCALE_G : SCALE_SIG;
    const float uv = U[k * G4_N + col] * scale;
    Upk[col * 64 + k] = bf16_rne(uv);
}

__global__ __launch_bounds__(256, 4) void char_lstm_mfma(
    const int* __restrict__ chars,    // [N][25]
    const ushort* __restrict__ Upk,   // [256][64] bf16-hi frag table
    const float* __restrict__ EWr,    // [128][64][4] permuted+scaled
    float* __restrict__ out)          // [N][64]
{
    const int j = threadIdx.x;
    const int w = j >> 6;            // wave 0..3
    const int l = j & 63;            // lane
    const int q = l >> 4;            // lane group 0..3
    const int n16 = l & 15;          // 0..15
    const int c16 = w * 16 + n16;    // this thread's unit/col-in-gate
    const int seq0 = blockIdx.x * SEQ_M;

    __shared__ int ibuf[TC_LEN][SEQ_M];              // byte offsets
    __shared__ ushort hbuf[2][2][SEQ_M * H_N];       // [buf][hi/lo], 8 KB

    // stage chars transposed as EWr BYTE offsets (row stride 256*4 = 1024)
    for (int idx = j; idx < TC_LEN * SEQ_M; idx += 256) {
        const int s = idx & 15, tt = idx >> 4;
        ibuf[tt][s] = chars[(seq0 + s) * TC_LEN + tt] << 10;
    }

    // ---- load pre-packed U-hi fragments: 8x dwordx4, L2-hot ----
    bf16x8 bh[4][2];
#pragma unroll
    for (int tile = 0; tile < 4; ++tile) {
        const ushort* ub = Upk + (tile * 64 + c16) * 64 + 8 * q;
#pragma unroll
        for (int ks = 0; ks < 2; ++ks)
            bh[tile][ks] = *(const bf16x8*)(ub + ks * 32);
    }

    __syncthreads();   // ibuf visible

    // hoisted LDS offsets + pre-biased EWr byte base
    const int offA0 = hswz(n16, 16 * q);
    const int offA1 = hswz(n16, 64 + 16 * q);
    int offW[4];
#pragma unroll
    for (int r = 0; r < 4; ++r) offW[r] = hswz(4 * q + r, c16 * 2);
    const char* ewb = (const char*)EWr + c16 * 16;

    float c[4] = {0.0f, 0.0f, 0.0f, 0.0f};
    f32x4 ewv[4];
    f32x4 acc[4];

    // activation on acc -> c update -> h; writes LDS planes or global
#define ACT_BODY(HN_HI, HN_LO, WRITE_OUT)                                     \
    {                                                                         \
        _Pragma("unroll")                                                     \
        for (int r = 0; r < 4; ++r) {                                         \
            const float A = __builtin_amdgcn_exp2f(acc[0][r]);                \
            const float B = __builtin_amdgcn_exp2f(acc[1][r]);                \
            const float C = __builtin_amdgcn_exp2f(acc[2][r]);                \
            const float D = __builtin_amdgcn_exp2f(acc[3][r]);                \
            const float di = 1.0f + A, df = 1.0f + B, dg = 1.0f + C;          \
            const float m1 = di * dg;                                         \
            const float num = fmaf(c[r], m1, (C - 1.0f) * df);                \
            c[r] = num * __builtin_amdgcn_rcpf(m1 * df);                      \
            const float E2 = __builtin_amdgcn_exp2f(c[r] * SCALE_G);          \
            const float nh = E2 - 1.0f;                                       \
            const float Ph = (1.0f + D) * (E2 + 1.0f);                        \
            const float h = nh * __builtin_amdgcn_rcpf(Ph);                   \
            if (WRITE_OUT) {                                                  \
                out[(seq0 + 4 * q + r) * H_N + c16] = h;                      \
            } else {                                                          \
                const uint hu = __float_as_uint(h);                           \
                const float hi_f = __uint_as_float(hu & 0xffff0000u);         \
                const float lo_f = h - hi_f;                                  \
                *(ushort*)((HN_HI) + offW[r]) = (ushort)(hu >> 16);           \
                *(ushort*)((HN_LO) + offW[r]) =                               \
                    (ushort)(__float_as_uint(lo_f) >> 16);                    \
            }                                                                 \
        }                                                                     \
    }

#define ACC_INIT()                                                            \
    {                                                                         \
        _Pragma("unroll")                                                     \
        for (int tile = 0; tile < 4; ++tile) {                                \
            acc[tile][0] = ewv[0][tile];                                      \
            acc[tile][1] = ewv[1][tile];                                      \
            acc[tile][2] = ewv[2][tile];                                      \
            acc[tile][3] = ewv[3][tile];                                      \
        }                                                                     \
    }

#define PREFETCH_EW(T1)                                                       \
    {                                                                         \
        const i32x4 cv = *(const i32x4*)&ibuf[(T1)][4 * q];                   \
        _Pragma("unroll")                                                     \
        for (int r = 0; r < 4; ++r)                                           \
            ewv[r] = *(const f32x4*)(ewb + cv[r]);                            \
    }

#define MFMA_CLUSTER(RB_HI, RB_LO)                                            \
    {                                                                         \
        const bf16x8 ah0 = *(const bf16x8*)((RB_HI) + offA0);                 \
        const bf16x8 al0 = *(const bf16x8*)((RB_LO) + offA0);                 \
        const bf16x8 ah1 = *(const bf16x8*)((RB_HI) + offA1);                 \
        const bf16x8 al1 = *(const bf16x8*)((RB_LO) + offA1);                 \
        __builtin_amdgcn_s_setprio(1);                                        \
        _Pragma("unroll")                                                     \
        for (int tile = 0; tile < 4; ++tile)                                  \
            acc[tile] = __builtin_amdgcn_mfma_f32_16x16x32_bf16(              \
                ah0, bh[tile][0], acc[tile], 0, 0, 0);                        \
        _Pragma("unroll")                                                     \
        for (int tile = 0; tile < 4; ++tile)                                  \
            acc[tile] = __builtin_amdgcn_mfma_f32_16x16x32_bf16(              \
                al0, bh[tile][0], acc[tile], 0, 0, 0);                        \
        _Pragma("unroll")                                                     \
        for (int tile = 0; tile < 4; ++tile)                                  \
            acc[tile] = __builtin_amdgcn_mfma_f32_16x16x32_bf16(              \
                ah1, bh[tile][1], acc[tile], 0, 0, 0);                        \
        _Pragma("unroll")                                                     \
        for (int tile = 0; tile < 4; ++tile)                                  \
            acc[tile] = __builtin_amdgcn_mfma_f32_16x16x32_bf16(              \
                al1, bh[tile][1], acc[tile], 0, 0, 0);                        \
        __builtin_amdgcn_s_setprio(0);                                        \
    }

    char* b0_hi = (char*)&hbuf[0][0][0];
    char* b0_lo = (char*)&hbuf[0][1][0];
    char* b1_hi = (char*)&hbuf[1][0][0];
    char* b1_lo = (char*)&hbuf[1][1][0];

    // ---- t = 0 (peeled): z = x-proj only, h0 -> buf0 ----
    PREFETCH_EW(0);
    ACC_INIT();
    PREFETCH_EW(1);
    ACT_BODY(b0_hi, b0_lo, false);
    __syncthreads();

    // ---- t = 1..22 as 11 static-parity pairs ----
    for (int tp = 0; tp < 11; ++tp) {
        // odd t: read buf0, write buf1
        ACC_INIT();
        PREFETCH_EW(2 * tp + 2);
        MFMA_CLUSTER(b0_hi, b0_lo);
        ACT_BODY(b1_hi, b1_lo, false);
        __syncthreads();
        // even t: read buf1, write buf0
        ACC_INIT();
        PREFETCH_EW(2 * tp + 3);
        MFMA_CLUSTER(b1_hi, b1_lo);
        ACT_BODY(b0_hi, b0_lo, false);
        __syncthreads();
    }

    // ---- t = 23: read buf0, write buf1 ----
    ACC_INIT();
    PREFETCH_EW(24);
    MFMA_CLUSTER(b0_hi, b0_lo);
    ACT_BODY(b1_hi, b1_lo, false);
    __syncthreads();

    // ---- t = 24 (peeled): read buf1, write h_last to GLOBAL ----
    ACC_INIT();
    MFMA_CLUSTER(b1_hi, b1_lo);
    ACT_BODY(b1_hi, b1_lo, true);

#undef ACT_BODY
#undef ACC_INIT
#undef PREFETCH_EW
#undef MFMA_CLUSTER
}

extern "C" void kernel_launch(void* const* d_in, const int* in_sizes, int n_in,
                              void* d_out, int out_size, void* d_ws, size_t ws_size,
                              hipStream_t stream) {
    const int*   chars = (const int*)d_in[0];
    const float* E     = (const float*)d_in[1];
    const float* W     = (const float*)d_in[2];
    const float* U     = (const float*)d_in[3];
    const float* b     = (const float*)d_in[4];
    float* out = (float*)d_out;
    float*  EWr = (float*)d_ws;                         // 131072 B
    ushort* Upk = (ushort*)((char*)d_ws + 131072);      // 32768 B

    const int N = in_sizes[0] / TC_LEN;             // 32768
    const int blocks = N / SEQ_M;                   // 2048

    ew_precompute<<<V_N, G4_N, 0, stream>>>(E, W, b, EWr);
    u_pack<<<H_N, G4_N, 0, stream>>>(U, Upk);
    char_lstm_mfma<<<blocks, 256, 0, stream>>>(chars, Upk, EWr, out);
}

// Round 12
// 85.415 us; speedup vs baseline: 1.7134x; 1.0279x over previous
//
#include <hip/hip_runtime.h>
#include <hip/hip_bf16.h>

// CharLSTM: B=128, TW=256, TC=25, V=128, D=32, H=64 (4H=256), N=32768 seqs.
//
// R12 = R11 + emitted-VALU diet (kernel is issue-dense: measured ~660
// VALU-cyc/wave-ts vs ~300 source-count -> cut EMITTED cycles):
//  - float2 (ext_vector) activation math -> v_pk_{add,mul,fma}_f32
//    dual-issue for the ~15 plain ALU ops per cell (trans stay scalar).
//  - zero-C MFMA: first MFMA per tile takes a persistent zero f32x4 as
//    C; "+EW" folds into the exp2 argument in ACT. Moves 16 movs off the
//    barrier->MFMA critical path (accvgpr-write burst gone).
//  - EW loads via uniform SGPR base + 32-bit voffset (saddr form)
//    instead of per-lane 64-bit pointer adds.

#define SEQ_M 16
#define TC_LEN 25
#define H_N 64
#define D_N 32
#define G4_N 256
#define V_N 128

typedef __attribute__((ext_vector_type(8))) short bf16x8;
typedef __attribute__((ext_vector_type(4))) float f32x4;
typedef __attribute__((ext_vector_type(2))) float f32x2;
typedef __attribute__((ext_vector_type(4))) int i32x4;

#define SCALE_SIG (-1.4426950408889634f)   /* -log2(e)  */
#define SCALE_G   ( 2.8853900817779268f)   /* 2*log2(e) */

__device__ __forceinline__ ushort bf16_rne(float x) {
    const uint u = __float_as_uint(x);
    return (ushort)((u + 0x7fffu + ((u >> 16) & 1u)) >> 16);
}
__device__ __forceinline__ float bf16_tof(ushort h) {
    return __uint_as_float(((uint)h) << 16);
}
// swizzled byte offset into a [16][64] bf16 (2 KB) tile
__device__ __forceinline__ int hswz(int row, int kbyte) {
    const int b = row * 128 + kbyte;
    return b ^ ((row & 7) << 4);
}

// ---- prologue 1: EWr[v][c16][tile] = ((E.W)[v][tile*64+c16]+b)*gate_scale ----
__global__ void ew_precompute(const float* __restrict__ E,
                              const float* __restrict__ W,
                              const float* __restrict__ b,
                              float* __restrict__ EWr) {
    const int v = blockIdx.x;
    const int j = threadIdx.x;           // output col = (j>>6)*64 + (j&63)
    float acc = b[j];
#pragma unroll
    for (int d = 0; d < D_N; ++d)
        acc = fmaf(E[v * D_N + d], W[d * G4_N + j], acc);
    const int tile = j >> 6, c16 = j & 63;
    const float scale = (tile == 2) ? SCALE_G : SCALE_SIG;
    EWr[v * G4_N + c16 * 4 + tile] = acc * scale;
}

// ---- prologue 2: Upk[col][k] bf16-hi, pre-scaled ----
__global__ void u_pack(const float* __restrict__ U, ushort* __restrict__ Upk) {
    const int k   = blockIdx.x;          // 0..63
    const int col = threadIdx.x;         // 0..255
    const float scale = ((col >> 6) == 2) ? SCALE_G : SCALE_SIG;
    const float uv = U[k * G4_N + col] * scale;
    Upk[col * 64 + k] = bf16_rne(uv);
}

__global__ __launch_bounds__(256, 4) void char_lstm_mfma(
    const int* __restrict__ chars,    // [N][25]
    const ushort* __restrict__ Upk,   // [256][64] bf16-hi frag table
    const float* __restrict__ EWr,    // [128][64][4] permuted+scaled
    float* __restrict__ out)          // [N][64]
{
    const int j = threadIdx.x;
    const int w = j >> 6;            // wave 0..3
    const int l = j & 63;            // lane
    const int q = l >> 4;            // lane group 0..3
    const int n16 = l & 15;          // 0..15
    const int c16 = w * 16 + n16;    // this thread's unit/col-in-gate
    const int seq0 = blockIdx.x * SEQ_M;

    __shared__ int ibuf[TC_LEN][SEQ_M];              // byte offsets
    __shared__ ushort hbuf[2][2][SEQ_M * H_N];       // [buf][hi/lo], 8 KB

    // stage chars transposed as EWr BYTE offsets (row stride 256*4 = 1024)
    for (int idx = j; idx < TC_LEN * SEQ_M; idx += 256) {
        const int s = idx & 15, tt = idx >> 4;
        ibuf[tt][s] = chars[(seq0 + s) * TC_LEN + tt] << 10;
    }

    // ---- load pre-packed U-hi fragments: 8x dwordx4, L2-hot ----
    bf16x8 bh[4][2];
#pragma unroll
    for (int tile = 0; tile < 4; ++tile) {
        const ushort* ub = Upk + (tile * 64 + c16) * 64 + 8 * q;
#pragma unroll
        for (int ks = 0; ks < 2; ++ks)
            bh[tile][ks] = *(const bf16x8*)(ub + ks * 32);
    }

    __syncthreads();   // ibuf visible

    // hoisted LDS offsets + uniform EW base with 32-bit per-lane offsets
    const int offA0 = hswz(n16, 16 * q);
    const int offA1 = hswz(n16, 64 + 16 * q);
    int offW[4];
#pragma unroll
    for (int r = 0; r < 4; ++r) offW[r] = hswz(4 * q + r, c16 * 2);
    const char* ewbase = (const char*)EWr;     // uniform -> SGPR pair
    const uint  c16b   = (uint)(c16 * 16);     // per-lane 32-bit bias

    f32x2 cP[2] = {{0.0f, 0.0f}, {0.0f, 0.0f}};
    f32x4 ewv[4];
    f32x4 acc[4];
    const f32x4 zero4 = {0.0f, 0.0f, 0.0f, 0.0f};

    // activation: z = (ADD_EW ? acc+ew : ew), packed f32x2 over r-pairs
#define ACT_BODY(HN_HI, HN_LO, ADD_EW, WRITE_OUT)                             \
    {                                                                         \
        _Pragma("unroll")                                                     \
        for (int p = 0; p < 2; ++p) {                                         \
            const int r0 = 2 * p, r1 = 2 * p + 1;                             \
            f32x2 z0, z1, z2, z3;                                             \
            if (ADD_EW) {                                                     \
                z0[0] = acc[0][r0] + ewv[r0][0]; z0[1] = acc[0][r1] + ewv[r1][0]; \
                z1[0] = acc[1][r0] + ewv[r0][1]; z1[1] = acc[1][r1] + ewv[r1][1]; \
                z2[0] = acc[2][r0] + ewv[r0][2]; z2[1] = acc[2][r1] + ewv[r1][2]; \
                z3[0] = acc[3][r0] + ewv[r0][3]; z3[1] = acc[3][r1] + ewv[r1][3]; \
            } else {                                                          \
                z0[0] = ewv[r0][0]; z0[1] = ewv[r1][0];                       \
                z1[0] = ewv[r0][1]; z1[1] = ewv[r1][1];                       \
                z2[0] = ewv[r0][2]; z2[1] = ewv[r1][2];                       \
                z3[0] = ewv[r0][3]; z3[1] = ewv[r1][3];                       \
            }                                                                 \
            f32x2 A, B, C, D;                                                 \
            A[0] = __builtin_amdgcn_exp2f(z0[0]); A[1] = __builtin_amdgcn_exp2f(z0[1]); \
            B[0] = __builtin_amdgcn_exp2f(z1[0]); B[1] = __builtin_amdgcn_exp2f(z1[1]); \
            C[0] = __builtin_amdgcn_exp2f(z2[0]); C[1] = __builtin_amdgcn_exp2f(z2[1]); \
            D[0] = __builtin_amdgcn_exp2f(z3[0]); D[1] = __builtin_amdgcn_exp2f(z3[1]); \
            const f32x2 di = A + 1.0f, df = B + 1.0f, dg = C + 1.0f;          \
            const f32x2 m1 = di * dg;                                         \
            const f32x2 num = cP[p] * m1 + (C - 1.0f) * df;                   \
            const f32x2 qa = m1 * df;                                         \
            f32x2 Q;                                                          \
            Q[0] = __builtin_amdgcn_rcpf(qa[0]);                              \
            Q[1] = __builtin_amdgcn_rcpf(qa[1]);                              \
            cP[p] = num * Q;                                                  \
            const f32x2 cs = cP[p] * SCALE_G;                                 \
            f32x2 E2;                                                         \
            E2[0] = __builtin_amdgcn_exp2f(cs[0]);                            \
            E2[1] = __builtin_amdgcn_exp2f(cs[1]);                            \
            const f32x2 nh = E2 - 1.0f;                                       \
            const f32x2 Ph = (D + 1.0f) * (E2 + 1.0f);                        \
            f32x2 R;                                                          \
            R[0] = __builtin_amdgcn_rcpf(Ph[0]);                              \
            R[1] = __builtin_amdgcn_rcpf(Ph[1]);                              \
            const f32x2 h = nh * R;                                           \
            _Pragma("unroll")                                                 \
            for (int e = 0; e < 2; ++e) {                                     \
                const int r = 2 * p + e;                                      \
                if (WRITE_OUT) {                                              \
                    out[(seq0 + 4 * q + r) * H_N + c16] = h[e];               \
                } else {                                                      \
                    const uint hu = __float_as_uint(h[e]);                    \
                    const float hi_f = __uint_as_float(hu & 0xffff0000u);     \
                    const float lo_f = h[e] - hi_f;                           \
                    *(ushort*)((HN_HI) + offW[r]) = (ushort)(hu >> 16);       \
                    *(ushort*)((HN_LO) + offW[r]) =                           \
                        (ushort)(__float_as_uint(lo_f) >> 16);                \
                }                                                             \
            }                                                                 \
        }                                                                     \
    }

#define PREFETCH_EW(T1)                                                       \
    {                                                                         \
        const i32x4 cv = *(const i32x4*)&ibuf[(T1)][4 * q];                   \
        _Pragma("unroll")                                                     \
        for (int r = 0; r < 4; ++r)                                           \
            ewv[r] = *(const f32x4*)(ewbase + (uint)(cv[r]) + c16b);          \
    }

    // first MFMA per tile takes zero4 as C -> no per-ts acc init
#define MFMA_CLUSTER(RB_HI, RB_LO)                                            \
    {                                                                         \
        const bf16x8 ah0 = *(const bf16x8*)((RB_HI) + offA0);                 \
        const bf16x8 al0 = *(const bf16x8*)((RB_LO) + offA0);                 \
        const bf16x8 ah1 = *(const bf16x8*)((RB_HI) + offA1);                 \
        const bf16x8 al1 = *(const bf16x8*)((RB_LO) + offA1);                 \
        __builtin_amdgcn_s_setprio(1);                                        \
        _Pragma("unroll")                                                     \
        for (int tile = 0; tile < 4; ++tile)                                  \
            acc[tile] = __builtin_amdgcn_mfma_f32_16x16x32_bf16(              \
                ah0, bh[tile][0], zero4, 0, 0, 0);                            \
        _Pragma("unroll")                                                     \
        for (int tile = 0; tile < 4; ++tile)                                  \
            acc[tile] = __builtin_amdgcn_mfma_f32_16x16x32_bf16(              \
                al0, bh[tile][0], acc[tile], 0, 0, 0);                        \
        _Pragma("unroll")                                                     \
        for (int tile = 0; tile < 4; ++tile)                                  \
            acc[tile] = __builtin_amdgcn_mfma_f32_16x16x32_bf16(              \
                ah1, bh[tile][1], acc[tile], 0, 0, 0);                        \
        _Pragma("unroll")                                                     \
        for (int tile = 0; tile < 4; ++tile)                                  \
            acc[tile] = __builtin_amdgcn_mfma_f32_16x16x32_bf16(              \
                al1, bh[tile][1], acc[tile], 0, 0, 0);                        \
        __builtin_amdgcn_s_setprio(0);                                        \
    }

    char* b0_hi = (char*)&hbuf[0][0][0];
    char* b0_lo = (char*)&hbuf[0][1][0];
    char* b1_hi = (char*)&hbuf[1][0][0];
    char* b1_lo = (char*)&hbuf[1][1][0];

    // ---- t = 0 (peeled): z = x-proj only, h0 -> buf0 ----
    PREFETCH_EW(0);
    ACT_BODY(b0_hi, b0_lo, 0, 0);
    PREFETCH_EW(1);
    __syncthreads();

    // ---- t = 1..22 as 11 static-parity pairs ----
    for (int tp = 0; tp < 11; ++tp) {
        // odd t: read buf0, write buf1
        MFMA_CLUSTER(b0_hi, b0_lo);
        ACT_BODY(b1_hi, b1_lo, 1, 0);
        PREFETCH_EW(2 * tp + 2);
        __syncthreads();
        // even t: read buf1, write buf0
        MFMA_CLUSTER(b1_hi, b1_lo);
        ACT_BODY(b0_hi, b0_lo, 1, 0);
        PREFETCH_EW(2 * tp + 3);
        __syncthreads();
    }

    // ---- t = 23: read buf0, write buf1 ----
    MFMA_CLUSTER(b0_hi, b0_lo);
    ACT_BODY(b1_hi, b1_lo, 1, 0);
    PREFETCH_EW(24);
    __syncthreads();

    // ---- t = 24 (peeled): read buf1, write h_last to GLOBAL ----
    MFMA_CLUSTER(b1_hi, b1_lo);
    ACT_BODY(b1_hi, b1_lo, 1, 1);

#undef ACT_BODY
#undef PREFETCH_EW
#undef MFMA_CLUSTER
}

extern "C" void kernel_launch(void* const* d_in, const int* in_sizes, int n_in,
                              void* d_out, int out_size, void* d_ws, size_t ws_size,
                              hipStream_t stream) {
    const int*   chars = (const int*)d_in[0];
    const float* E     = (const float*)d_in[1];
    const float* W     = (const float*)d_in[2];
    const float* U     = (const float*)d_in[3];
    const float* b     = (const float*)d_in[4];
    float* out = (float*)d_out;
    float*  EWr = (float*)d_ws;                         // 131072 B
    ushort* Upk = (ushort*)((char*)d_ws + 131072);      // 32768 B

    const int N = in_sizes[0] / TC_LEN;             // 32768
    const int blocks = N / SEQ_M;                   // 2048

    ew_precompute<<<V_N, G4_N, 0, stream>>>(E, W, b, EWr);
    u_pack<<<H_N, G4_N, 0, stream>>>(U, Upk);
    char_lstm_mfma<<<blocks, 256, 0, stream>>>(chars, Upk, EWr, out);
}

// Round 13
// 72.330 us; speedup vs baseline: 2.0233x; 1.1809x over previous
//
#include <hip/hip_runtime.h>
#include <hip/hip_bf16.h>

// CharLSTM: B=128, TW=256, TC=25, V=128, D=32, H=64 (4H=256), N=32768 seqs.
//
// R13 = R12 with the h-lo correction term dropped (single-term MFMA):
//  - h stored as bf16 with RNE rounding (was truncation-hi + lo plane).
//    Error budget: sigma_z ~3e-4 scaled, recurrence amplification ~2x,
//    predicted absmax 0.8-1.5e-3 vs threshold 1.816e-3. Declared
//    fallback: revert to R12 (85.4 us) if absmax fails.
//  - MFMA 16 -> 8 per wave-ts (chains 2-deep), cluster ds_reads 4 -> 2,
//    ds_writes 8 -> 4, lo-plane pack (~16 instr) gone, hbuf 8 -> 4 KB.

#define SEQ_M 16
#define TC_LEN 25
#define H_N 64
#define D_N 32
#define G4_N 256
#define V_N 128

typedef __attribute__((ext_vector_type(8))) short bf16x8;
typedef __attribute__((ext_vector_type(4))) float f32x4;
typedef __attribute__((ext_vector_type(2))) float f32x2;
typedef __attribute__((ext_vector_type(4))) int i32x4;

#define SCALE_SIG (-1.4426950408889634f)   /* -log2(e)  */
#define SCALE_G   ( 2.8853900817779268f)   /* 2*log2(e) */

__device__ __forceinline__ ushort bf16_rne(float x) {
    const uint u = __float_as_uint(x);
    return (ushort)((u + 0x7fffu + ((u >> 16) & 1u)) >> 16);
}
__device__ __forceinline__ float bf16_tof(ushort h) {
    return __uint_as_float(((uint)h) << 16);
}
// swizzled byte offset into a [16][64] bf16 (2 KB) tile
__device__ __forceinline__ int hswz(int row, int kbyte) {
    const int b = row * 128 + kbyte;
    return b ^ ((row & 7) << 4);
}

// ---- prologue 1: EWr[v][c16][tile] = ((E.W)[v][tile*64+c16]+b)*gate_scale ----
__global__ void ew_precompute(const float* __restrict__ E,
                              const float* __restrict__ W,
                              const float* __restrict__ b,
                              float* __restrict__ EWr) {
    const int v = blockIdx.x;
    const int j = threadIdx.x;           // output col = (j>>6)*64 + (j&63)
    float acc = b[j];
#pragma unroll
    for (int d = 0; d < D_N; ++d)
        acc = fmaf(E[v * D_N + d], W[d * G4_N + j], acc);
    const int tile = j >> 6, c16 = j & 63;
    const float scale = (tile == 2) ? SCALE_G : SCALE_SIG;
    EWr[v * G4_N + c16 * 4 + tile] = acc * scale;
}

// ---- prologue 2: Upk[col][k] bf16-hi, pre-scaled ----
__global__ void u_pack(const float* __restrict__ U, ushort* __restrict__ Upk) {
    const int k   = blockIdx.x;          // 0..63
    const int col = threadIdx.x;         // 0..255
    const float scale = ((col >> 6) == 2) ? SCALE_G : SCALE_SIG;
    const float uv = U[k * G4_N + col] * scale;
    Upk[col * 64 + k] = bf16_rne(uv);
}

__global__ __launch_bounds__(256, 4) void char_lstm_mfma(
    const int* __restrict__ chars,    // [N][25]
    const ushort* __restrict__ Upk,   // [256][64] bf16-hi frag table
    const float* __restrict__ EWr,    // [128][64][4] permuted+scaled
    float* __restrict__ out)          // [N][64]
{
    const int j = threadIdx.x;
    const int w = j >> 6;            // wave 0..3
    const int l = j & 63;            // lane
    const int q = l >> 4;            // lane group 0..3
    const int n16 = l & 15;          // 0..15
    const int c16 = w * 16 + n16;    // this thread's unit/col-in-gate
    const int seq0 = blockIdx.x * SEQ_M;

    __shared__ int ibuf[TC_LEN][SEQ_M];              // byte offsets
    __shared__ ushort hbuf[2][SEQ_M * H_N];          // [buf], bf16-RNE h, 4 KB

    // stage chars transposed as EWr BYTE offsets (row stride 256*4 = 1024)
    for (int idx = j; idx < TC_LEN * SEQ_M; idx += 256) {
        const int s = idx & 15, tt = idx >> 4;
        ibuf[tt][s] = chars[(seq0 + s) * TC_LEN + tt] << 10;
    }

    // ---- load pre-packed U-hi fragments: 8x dwordx4, L2-hot ----
    bf16x8 bh[4][2];
#pragma unroll
    for (int tile = 0; tile < 4; ++tile) {
        const ushort* ub = Upk + (tile * 64 + c16) * 64 + 8 * q;
#pragma unroll
        for (int ks = 0; ks < 2; ++ks)
            bh[tile][ks] = *(const bf16x8*)(ub + ks * 32);
    }

    __syncthreads();   // ibuf visible

    // hoisted LDS offsets + uniform EW base with 32-bit per-lane offsets
    const int offA0 = hswz(n16, 16 * q);
    const int offA1 = hswz(n16, 64 + 16 * q);
    int offW[4];
#pragma unroll
    for (int r = 0; r < 4; ++r) offW[r] = hswz(4 * q + r, c16 * 2);
    const char* ewbase = (const char*)EWr;     // uniform -> SGPR pair
    const uint  c16b   = (uint)(c16 * 16);     // per-lane 32-bit bias

    f32x2 cP[2] = {{0.0f, 0.0f}, {0.0f, 0.0f}};
    f32x4 ewv[4];
    f32x4 acc[4];
    const f32x4 zero4 = {0.0f, 0.0f, 0.0f, 0.0f};

    // activation: z = (ADD_EW ? acc+ew : ew), packed f32x2 over r-pairs
#define ACT_BODY(HN, ADD_EW, WRITE_OUT)                                       \
    {                                                                         \
        _Pragma("unroll")                                                     \
        for (int p = 0; p < 2; ++p) {                                         \
            const int r0 = 2 * p, r1 = 2 * p + 1;                             \
            f32x2 z0, z1, z2, z3;                                             \
            if (ADD_EW) {                                                     \
                z0[0] = acc[0][r0] + ewv[r0][0]; z0[1] = acc[0][r1] + ewv[r1][0]; \
                z1[0] = acc[1][r0] + ewv[r0][1]; z1[1] = acc[1][r1] + ewv[r1][1]; \
                z2[0] = acc[2][r0] + ewv[r0][2]; z2[1] = acc[2][r1] + ewv[r1][2]; \
                z3[0] = acc[3][r0] + ewv[r0][3]; z3[1] = acc[3][r1] + ewv[r1][3]; \
            } else {                                                          \
                z0[0] = ewv[r0][0]; z0[1] = ewv[r1][0];                       \
                z1[0] = ewv[r0][1]; z1[1] = ewv[r1][1];                       \
                z2[0] = ewv[r0][2]; z2[1] = ewv[r1][2];                       \
                z3[0] = ewv[r0][3]; z3[1] = ewv[r1][3];                       \
            }                                                                 \
            f32x2 A, B, C, D;                                                 \
            A[0] = __builtin_amdgcn_exp2f(z0[0]); A[1] = __builtin_amdgcn_exp2f(z0[1]); \
            B[0] = __builtin_amdgcn_exp2f(z1[0]); B[1] = __builtin_amdgcn_exp2f(z1[1]); \
            C[0] = __builtin_amdgcn_exp2f(z2[0]); C[1] = __builtin_amdgcn_exp2f(z2[1]); \
            D[0] = __builtin_amdgcn_exp2f(z3[0]); D[1] = __builtin_amdgcn_exp2f(z3[1]); \
            const f32x2 di = A + 1.0f, df = B + 1.0f, dg = C + 1.0f;          \
            const f32x2 m1 = di * dg;                                         \
            const f32x2 num = cP[p] * m1 + (C - 1.0f) * df;                   \
            const f32x2 qa = m1 * df;                                         \
            f32x2 Q;                                                          \
            Q[0] = __builtin_amdgcn_rcpf(qa[0]);                              \
            Q[1] = __builtin_amdgcn_rcpf(qa[1]);                              \
            cP[p] = num * Q;                                                  \
            const f32x2 cs = cP[p] * SCALE_G;                                 \
            f32x2 E2;                                                         \
            E2[0] = __builtin_amdgcn_exp2f(cs[0]);                            \
            E2[1] = __builtin_amdgcn_exp2f(cs[1]);                            \
            const f32x2 nh = E2 - 1.0f;                                       \
            const f32x2 Ph = (D + 1.0f) * (E2 + 1.0f);                        \
            f32x2 R;                                                          \
            R[0] = __builtin_amdgcn_rcpf(Ph[0]);                              \
            R[1] = __builtin_amdgcn_rcpf(Ph[1]);                              \
            const f32x2 h = nh * R;                                           \
            _Pragma("unroll")                                                 \
            for (int e = 0; e < 2; ++e) {                                     \
                const int r = 2 * p + e;                                      \
                if (WRITE_OUT) {                                              \
                    out[(seq0 + 4 * q + r) * H_N + c16] = h[e];               \
                } else {                                                      \
                    *(ushort*)((HN) + offW[r]) = bf16_rne(h[e]);              \
                }                                                             \
            }                                                                 \
        }                                                                     \
    }

#define PREFETCH_EW(T1)                                                       \
    {                                                                         \
        const i32x4 cv = *(const i32x4*)&ibuf[(T1)][4 * q];                   \
        _Pragma("unroll")                                                     \
        for (int r = 0; r < 4; ++r)                                           \
            ewv[r] = *(const f32x4*)(ewbase + (uint)(cv[r]) + c16b);          \
    }

    // single-term: 8 MFMA, 2-deep chains, zero-C first op
#define MFMA_CLUSTER(RB)                                                      \
    {                                                                         \
        const bf16x8 ah0 = *(const bf16x8*)((RB) + offA0);                    \
        const bf16x8 ah1 = *(const bf16x8*)((RB) + offA1);                    \
        __builtin_amdgcn_s_setprio(1);                                        \
        _Pragma("unroll")                                                     \
        for (int tile = 0; tile < 4; ++tile)                                  \
            acc[tile] = __builtin_amdgcn_mfma_f32_16x16x32_bf16(              \
                ah0, bh[tile][0], zero4, 0, 0, 0);                            \
        _Pragma("unroll")                                                     \
        for (int tile = 0; tile < 4; ++tile)                                  \
            acc[tile] = __builtin_amdgcn_mfma_f32_16x16x32_bf16(              \
                ah1, bh[tile][1], acc[tile], 0, 0, 0);                        \
        __builtin_amdgcn_s_setprio(0);                                        \
    }

    char* b0 = (char*)&hbuf[0][0];
    char* b1 = (char*)&hbuf[1][0];

    // ---- t = 0 (peeled): z = x-proj only, h0 -> buf0 ----
    PREFETCH_EW(0);
    ACT_BODY(b0, 0, 0);
    PREFETCH_EW(1);
    __syncthreads();

    // ---- t = 1..22 as 11 static-parity pairs ----
    for (int tp = 0; tp < 11; ++tp) {
        // odd t: read buf0, write buf1
        MFMA_CLUSTER(b0);
        ACT_BODY(b1, 1, 0);
        PREFETCH_EW(2 * tp + 2);
        __syncthreads();
        // even t: read buf1, write buf0
        MFMA_CLUSTER(b1);
        ACT_BODY(b0, 1, 0);
        PREFETCH_EW(2 * tp + 3);
        __syncthreads();
    }

    // ---- t = 23: read buf0, write buf1 ----
    MFMA_CLUSTER(b0);
    ACT_BODY(b1, 1, 0);
    PREFETCH_EW(24);
    __syncthreads();

    // ---- t = 24 (peeled): read buf1, write h_last to GLOBAL (f32 regs) ----
    MFMA_CLUSTER(b1);
    ACT_BODY(b1, 1, 1);

#undef ACT_BODY
#undef PREFETCH_EW
#undef MFMA_CLUSTER
}

extern "C" void kernel_launch(void* const* d_in, const int* in_sizes, int n_in,
                              void* d_out, int out_size, void* d_ws, size_t ws_size,
                              hipStream_t stream) {
    const int*   chars = (const int*)d_in[0];
    const float* E     = (const float*)d_in[1];
    const float* W     = (const float*)d_in[2];
    const float* U     = (const float*)d_in[3];
    const float* b     = (const float*)d_in[4];
    float* out = (float*)d_out;
    float*  EWr = (float*)d_ws;                         // 131072 B
    ushort* Upk = (ushort*)((char*)d_ws + 131072);      // 32768 B

    const int N = in_sizes[0] / TC_LEN;             // 32768
    const int blocks = N / SEQ_M;                   // 2048

    ew_precompute<<<V_N, G4_N, 0, stream>>>(E, W, b, EWr);
    u_pack<<<H_N, G4_N, 0, stream>>>(U, Upk);
    char_lstm_mfma<<<blocks, 256, 0, stream>>>(chars, Upk, EWr, out);
}